// Round 13
// baseline (87.082 us; speedup 1.0000x reference)
//
#include <hip/hip_runtime.h>
#include <math.h>

// Problem constants (from reference)
#define HH 256
#define WW 256
#define CC 256
#define HW 65536
#define NPTS 1024
#define BB 2            // batch after indexing (BW=4, WINDOW_SIZE=2)
#define KEEP 13         // int(3.0 // 0.25 + 1)
#define KEEPM 14        // window + 1 margin for bilinear corners
#define TINV 100.0f     // 1 / SOFTMAX_TEMP
#define EPSN 1e-12f
#define S_ALL 8355840.0f  // sum over all HW positions of u (== of v)

// Tiling for the dense correlation pass: 16x4 px tiles, 256-thread blocks,
// 4-way channel-split lanes (quarter = lane>>4, pxg = lane&15).
#define CTW 16          // tile width (pixels, u)
#define CTH 4           // tile height (pixels, v)
#define CTUN 16         // tiles per row (256/16)
#define CTPB 1024       // tiles per batch (16 * 64)
#define CNT (BB * CTPB) // 2048 tiles total
#define CAPT 192        // max keypoints listed per tile (LDS list)
#define VSTRIDE 864     // padded per-keypoint margin capacity (>= 29*29=841)
#define BPADH 40        // B_h row stride (ushorts): 80B rows, 16B-aligned k8
#define KPB 64          // keypoints per prep_src block

__device__ __forceinline__ unsigned int f2bf(float x) {
    unsigned int u = __float_as_uint(x);
    return (u + 0x8000u) >> 16;       // round-to-nearest-ish bf16
}

// ---------------- prep: normalize src descriptors via LDS transpose ---------
__global__ __launch_bounds__(256) void prep_src(const float* __restrict__ kdesc,
                                                const float* __restrict__ kcoords,
                                                float* __restrict__ srcn,
                                                unsigned int* __restrict__ kparams) {
    __shared__ float tr[KPB][CC + 1];   // [kpt][ch], pad -> conflict-free
    __shared__ float red[4][KPB];
    __shared__ float s_inv[KPB];
    int t = threadIdx.x;
    int kpt0 = blockIdx.x * KPB;
    int b = kpt0 >> 10;
    int n0 = kpt0 & 1023;
    const float* srcbase = kdesc + (size_t)(2 * b) * CC * NPTS;  // kp_inds = 2b

    int cj = t >> 6, nj = t & 63;
    for (int c0 = 0; c0 < CC; c0 += 4)   // coalesced 256B row reads
        tr[nj][c0 + cj] = srcbase[(size_t)(c0 + cj) * NPTS + n0 + nj];
    __syncthreads();

    {   // norms: kpt j = t&63, part p = t>>6 over 64 channels
        int j = t & 63, p = t >> 6;
        float ss = 0.f;
#pragma unroll 8
        for (int i = 0; i < 64; i++) {
            float x = tr[j][p * 64 + i];
            ss = fmaf(x, x, ss);
        }
        red[p][j] = ss;
    }
    __syncthreads();
    if (t < KPB) {
        float ss = red[0][t] + red[1][t] + red[2][t] + red[3][t];
        s_inv[t] = 1.0f / fmaxf(sqrtf(ss), EPSN);
        int kpt = kpt0 + t;
        int n = kpt & 1023;
        float cu = kcoords[((size_t)(2 * b) * NPTS + n) * 2 + 0];
        float cv = kcoords[((size_t)(2 * b) * NPTS + n) * 2 + 1];
        int u = (int)truncf(cu), v = (int)truncf(cv);
        int u0m = max(0, u - KEEPM), u1m = min(WW - 1, u + KEEPM);
        int v0m = max(0, v - KEEPM), v1m = min(HH - 1, v + KEEPM);
        int nWm = u1m - u0m + 1, nHm = v1m - v0m + 1;
        kparams[kpt] = (unsigned)u0m | ((unsigned)v0m << 8) |
                       ((unsigned)nWm << 16) | ((unsigned)nHm << 24);
    }
    __syncthreads();
    for (int j = 0; j < KPB; j++)        // coalesced 1KB row writes
        srcn[(size_t)(kpt0 + j) * CC + t] = tr[j][t] * s_inv[j];
}

// ---------------- dense correlation per tile (with inline binning) ----------
// Block = 256 threads = one 16x4 pixel tile.
// lane = (quarter = lane>>4: channel mod 4, pxg = lane&15: pixel quad)
// kg = t>>6 (WAVE-UNIFORM 8-kpt group; 4 waves x 8 = 32 slots/chunk).
// B stored in LDS as bf16 (20KB) -> ~6 blocks/CU instead of 4.
__global__ __launch_bounds__(256) void corr_tiles(const float* __restrict__ ddense,
                                                  const float* __restrict__ srcn,
                                                  const unsigned int* __restrict__ kparams,
                                                  float* __restrict__ vals,
                                                  float* __restrict__ invn) {
    __shared__ __align__(16) unsigned short B_h[CC][BPADH];  // bf16 B, 20KB
    __shared__ float s_inorm[CTW * CTH];   // 64 per-pixel inverse norms
    __shared__ int s_kid[CAPT];
    __shared__ unsigned int s_kp[CAPT];
    __shared__ int s_cnt;

    int tileg = blockIdx.x;
    int b = tileg >> 10, tl = tileg & 1023;
    int tv = tl >> 4, tu = tl & 15;
    int vb = tv * CTH, ub = tu * CTW;
    int t = threadIdx.x;
    if (t == 0) s_cnt = 0;
    __syncthreads();

    // inline binning: scan this batch's 1024 keypoints for margin-box overlap
    for (int i = t; i < NPTS; i += 256) {
        unsigned int kp = kparams[b * NPTS + i];
        int u0m = kp & 255, v0m = (kp >> 8) & 255;
        int nWm = (kp >> 16) & 255, nHm = (int)(kp >> 24);
        if (u0m <= ub + CTW - 1 && u0m + nWm - 1 >= ub &&
            v0m <= vb + CTH - 1 && v0m + nHm - 1 >= vb) {
            int slot = atomicAdd(&s_cnt, 1);
            if (slot < CAPT) {
                s_kid[slot] = b * NPTS + i;
                s_kp[slot] = kp;
            }
        }
    }
    __syncthreads();
    int nk = min(s_cnt, CAPT);
    if (nk == 0) return;

    int lane = t & 63;
    int quarter = lane >> 4;         // channel mod 4
    int pxg = lane & 15;             // pixel quad 0..15
    int kg = t >> 6;                 // wave id 0..3 -> 8-kpt group (uniform)
    int k8 = kg * 8;
    int px4 = pxg * 4;
    int wv = vb + (px4 >> 4), wu0 = ub + (px4 & 15);
    const float* abase = ddense + (size_t)(2 * b + 1) * CC * HW +
                         (size_t)quarter * HW + (size_t)wv * WW + wu0;

    for (int kc = 0; kc < nk; kc += 32) {
        int nkk = min(32, nk - kc);
        // stage B chunk as bf16 pairs (16 packed u32 writes per channel row)
        {
            unsigned int* row = (unsigned int*)&B_h[t][0];
#pragma unroll 4
            for (int i = 0; i < 32; i += 2) {
                unsigned int lo = (i < nkk)
                    ? f2bf(srcn[(size_t)s_kid[kc + i] * CC + t]) : 0u;
                unsigned int hi = (i + 1 < nkk)
                    ? f2bf(srcn[(size_t)s_kid[kc + i + 1] * CC + t]) : 0u;
                row[i >> 1] = lo | (hi << 16);
            }
        }
        __syncthreads();

        float acc[4][8];
#pragma unroll
        for (int i = 0; i < 4; i++)
#pragma unroll
            for (int j = 0; j < 8; j++) acc[i][j] = 0.f;

        int kgn = (nkk + 7) >> 3;    // waves actually needed (uniform skip)
        if (kg < kgn) {
            float ss0 = 0.f, ss1 = 0.f, ss2 = 0.f, ss3 = 0.f;
            bool dos = (kg == 0) && (kc == 0);
#pragma unroll 4
            for (int cc = 0; cc < CC / 4; cc++) {   // 64 iters, 4-ch stride
                float4 av = *(const float4*)(abase + (size_t)cc * (4 * HW));
                uint4 bv = *(const uint4*)(&B_h[4 * cc + quarter][k8]);
                float b0 = __uint_as_float(bv.x << 16);
                float b1 = __uint_as_float(bv.x & 0xffff0000u);
                float b2 = __uint_as_float(bv.y << 16);
                float b3 = __uint_as_float(bv.y & 0xffff0000u);
                float b4 = __uint_as_float(bv.z << 16);
                float b5 = __uint_as_float(bv.z & 0xffff0000u);
                float b6 = __uint_as_float(bv.w << 16);
                float b7 = __uint_as_float(bv.w & 0xffff0000u);
                acc[0][0] = fmaf(av.x, b0, acc[0][0]);
                acc[0][1] = fmaf(av.x, b1, acc[0][1]);
                acc[0][2] = fmaf(av.x, b2, acc[0][2]);
                acc[0][3] = fmaf(av.x, b3, acc[0][3]);
                acc[0][4] = fmaf(av.x, b4, acc[0][4]);
                acc[0][5] = fmaf(av.x, b5, acc[0][5]);
                acc[0][6] = fmaf(av.x, b6, acc[0][6]);
                acc[0][7] = fmaf(av.x, b7, acc[0][7]);
                acc[1][0] = fmaf(av.y, b0, acc[1][0]);
                acc[1][1] = fmaf(av.y, b1, acc[1][1]);
                acc[1][2] = fmaf(av.y, b2, acc[1][2]);
                acc[1][3] = fmaf(av.y, b3, acc[1][3]);
                acc[1][4] = fmaf(av.y, b4, acc[1][4]);
                acc[1][5] = fmaf(av.y, b5, acc[1][5]);
                acc[1][6] = fmaf(av.y, b6, acc[1][6]);
                acc[1][7] = fmaf(av.y, b7, acc[1][7]);
                acc[2][0] = fmaf(av.z, b0, acc[2][0]);
                acc[2][1] = fmaf(av.z, b1, acc[2][1]);
                acc[2][2] = fmaf(av.z, b2, acc[2][2]);
                acc[2][3] = fmaf(av.z, b3, acc[2][3]);
                acc[2][4] = fmaf(av.z, b4, acc[2][4]);
                acc[2][5] = fmaf(av.z, b5, acc[2][5]);
                acc[2][6] = fmaf(av.z, b6, acc[2][6]);
                acc[2][7] = fmaf(av.z, b7, acc[2][7]);
                acc[3][0] = fmaf(av.w, b0, acc[3][0]);
                acc[3][1] = fmaf(av.w, b1, acc[3][1]);
                acc[3][2] = fmaf(av.w, b2, acc[3][2]);
                acc[3][3] = fmaf(av.w, b3, acc[3][3]);
                acc[3][4] = fmaf(av.w, b4, acc[3][4]);
                acc[3][5] = fmaf(av.w, b5, acc[3][5]);
                acc[3][6] = fmaf(av.w, b6, acc[3][6]);
                acc[3][7] = fmaf(av.w, b7, acc[3][7]);
                if (dos) {          // wave-0-only pixel-norm accumulation
                    ss0 = fmaf(av.x, av.x, ss0);
                    ss1 = fmaf(av.y, av.y, ss1);
                    ss2 = fmaf(av.z, av.z, ss2);
                    ss3 = fmaf(av.w, av.w, ss3);
                }
            }
            // combine the 4 channel-quarters: butterfly over lane bits 4,5
#pragma unroll
            for (int i = 0; i < 4; i++)
#pragma unroll
                for (int j = 0; j < 8; j++) {
                    acc[i][j] += __shfl_xor(acc[i][j], 16, 64);
                    acc[i][j] += __shfl_xor(acc[i][j], 32, 64);
                }
            if (dos) {
                ss0 += __shfl_xor(ss0, 16, 64);
                ss0 += __shfl_xor(ss0, 32, 64);
                ss1 += __shfl_xor(ss1, 16, 64);
                ss1 += __shfl_xor(ss1, 32, 64);
                ss2 += __shfl_xor(ss2, 16, 64);
                ss2 += __shfl_xor(ss2, 32, 64);
                ss3 += __shfl_xor(ss3, 16, 64);
                ss3 += __shfl_xor(ss3, 32, 64);
                if (quarter == 0) {
                    float i0 = 1.0f / fmaxf(sqrtf(ss0), EPSN);
                    float i1 = 1.0f / fmaxf(sqrtf(ss1), EPSN);
                    float i2 = 1.0f / fmaxf(sqrtf(ss2), EPSN);
                    float i3 = 1.0f / fmaxf(sqrtf(ss3), EPSN);
                    s_inorm[px4 + 0] = i0;
                    s_inorm[px4 + 1] = i1;
                    s_inorm[px4 + 2] = i2;
                    s_inorm[px4 + 3] = i3;
                    float* ip = invn + (size_t)b * HW + wv * WW + wu0;
                    ip[0] = i0; ip[1] = i1; ip[2] = i2; ip[3] = i3;
                }
            }
        }
        if (kc == 0) __syncthreads();   // publish s_inorm before first scatter

        // scatter NORMALIZED window values from quarter-0 lanes
        // j-outer: decode each keypoint ONCE, hoist the row (dv) check.
        if (quarter == 0) {
            float iv0 = s_inorm[px4 + 0], iv1 = s_inorm[px4 + 1];
            float iv2 = s_inorm[px4 + 2], iv3 = s_inorm[px4 + 3];
#pragma unroll
            for (int j = 0; j < 8; j++) {
                int s = k8 + j;
                if (s < nkk) {
                    unsigned int kp = s_kp[kc + s];
                    int u0m = kp & 255, v0m = (kp >> 8) & 255;
                    int nWm = (kp >> 16) & 255, nHm = (int)(kp >> 24);
                    int dv = wv - v0m;
                    if ((unsigned)dv < (unsigned)nHm) {
                        int du0 = wu0 - u0m;
                        float* vp = vals + (size_t)s_kid[kc + s] * VSTRIDE +
                                    dv * nWm;
                        if ((unsigned)(du0 + 0) < (unsigned)nWm)
                            vp[du0 + 0] = acc[0][j] * iv0;
                        if ((unsigned)(du0 + 1) < (unsigned)nWm)
                            vp[du0 + 1] = acc[1][j] * iv1;
                        if ((unsigned)(du0 + 2) < (unsigned)nWm)
                            vp[du0 + 2] = acc[2][j] * iv2;
                        if ((unsigned)(du0 + 3) < (unsigned)nWm)
                            vp[du0 + 3] = acc[3][j] * iv3;
                    }
                }
            }
        }
        __syncthreads();   // protect B_h before next chunk's staging
    }
}

// ---------------- reductions helper -----------------------------------------
__device__ inline float blockSum(float v, float* sred, int t) {
    for (int o = 32; o > 0; o >>= 1) v += __shfl_down(v, o, 64);
    __syncthreads();
    if ((t & 63) == 0) sred[t >> 6] = v;
    __syncthreads();
    return sred[0] + sred[1] + sred[2] + sred[3];
}

// ---------------- finish: softmax-argmax + resample from normalized vals ----
__global__ __launch_bounds__(256) void finish(const float* __restrict__ kscores,
                                              const float* __restrict__ sdense,
                                              const float* __restrict__ ddense,
                                              const float* __restrict__ kcoords,
                                              const float* __restrict__ srcn,
                                              const float* __restrict__ vals,
                                              const float* __restrict__ invn,
                                              float* __restrict__ out) {
    __shared__ float s_src[CC];
    __shared__ float s_red[4];
    int t = threadIdx.x;
    int kpt = blockIdx.x;
    int b = kpt >> 10, n = kpt & 1023;

    s_src[t] = srcn[(size_t)kpt * CC + t];

    float cu = kcoords[((size_t)(2 * b) * NPTS + n) * 2 + 0];
    float cv = kcoords[((size_t)(2 * b) * NPTS + n) * 2 + 1];
    int u = (int)truncf(cu), v = (int)truncf(cv);
    int u0 = max(0, u - KEEP), u1 = min(WW - 1, u + KEEP);
    int v0 = max(0, v - KEEP), v1 = min(HH - 1, v + KEEP);
    int nW = u1 - u0 + 1, nH = v1 - v0 + 1;
    int cnt = nW * nH;
    int u0m = max(0, u - KEEPM), u1m = min(WW - 1, u + KEEPM);
    int v0m = max(0, v - KEEPM), v1m = min(HH - 1, v + KEEPM);
    int nWm = u1m - u0m + 1, nHm = v1m - v0m + 1;
    int cntm = nWm * nHm;

    const float* vrow = vals + (size_t)kpt * VSTRIDE;
    __syncthreads();

    float valk[4];
    int puk[4], pvk[4];
    bool gk[4];
    float lm = -INFINITY;
#pragma unroll
    for (int k = 0; k < 4; k++) {
        int p = t + k * 256;
        bool gm = p < cntm;
        int pp = gm ? p : 0;
        int dvm = pp / nWm, dum = pp - dvm * nWm;
        int pu = u0m + dum, pv = v0m + dvm;
        bool inw = gm && pu >= u0 && pu <= u1 && pv >= v0 && pv <= v1;
        float val = inw ? vrow[pp] : 0.f;   // already normalized
        valk[k] = val;
        puk[k] = pu;
        pvk[k] = pv;
        gk[k] = inw;
        if (inw) lm = fmaxf(lm, val);
    }

    for (int o = 32; o > 0; o >>= 1) lm = fmaxf(lm, __shfl_down(lm, o, 64));
    if ((t & 63) == 0) s_red[t >> 6] = lm;
    __syncthreads();
    float m = fmaxf(fmaxf(s_red[0], s_red[1]), fmaxf(s_red[2], s_red[3]));
    m = fmaxf(m, 0.0f);

    float pse = 0.f, psu = 0.f, psv = 0.f;
#pragma unroll
    for (int k = 0; k < 4; k++) {
        float e = gk[k] ? expf(TINV * (valk[k] - m)) : 0.f;
        pse += e;
        psu = fmaf(e, (float)puk[k], psu);
        psv = fmaf(e, (float)pvk[k], psv);
    }
    float se = blockSum(pse, s_red, t);
    float su = blockSum(psu, s_red, t);
    float sv = blockSum(psv, s_red, t);

    float em = expf(-TINV * m);
    float sumWinU = 0.5f * (float)(u0 + u1) * (float)nW * (float)nH;
    float sumWinV = 0.5f * (float)(v0 + v1) * (float)nH * (float)nW;
    float denom = se + (65536.0f - (float)cnt) * em;
    float pcu = (su + em * (S_ALL - sumWinU)) / denom;
    float pcv = (sv + em * (S_ALL - sumWinV)) / denom;

    if (t == 0) {
        out[((size_t)b * NPTS + n) * 2 + 0] = pcu;
        out[((size_t)b * NPTS + n) * 2 + 1] = pcv;
    }

    // bilinear resample (align_corners=False, zero padding)
    float x = pcu * (256.0f / 255.0f) - 0.5f;
    float y = pcv * (256.0f / 255.0f) - 0.5f;
    float x0f = floorf(x), y0f = floorf(y);
    float wx = x - x0f, wy = y - y0f;
    int xi0 = (int)x0f, yi0 = (int)y0f, xi1 = xi0 + 1, yi1 = yi0 + 1;
    float w00 = (1.f - wx) * (1.f - wy), w10 = wx * (1.f - wy);
    float w01 = (1.f - wx) * wy, w11 = wx * wy;
    bool vx0 = (xi0 >= 0) & (xi0 < WW), vx1 = (xi1 >= 0) & (xi1 < WW);
    bool vy0 = (yi0 >= 0) & (yi0 < HH), vy1 = (yi1 >= 0) & (yi1 < HH);
    int cx0 = min(max(xi0, 0), WW - 1), cx1 = min(max(xi1, 0), WW - 1);
    int cy0 = min(max(yi0, 0), HH - 1), cy1 = min(max(yi1, 0), HH - 1);

    int cxs[4] = {cx0, cx1, cx0, cx1};
    int cys[4] = {cy0, cy0, cy1, cy1};
    bool cvalid[4] = {vx0 && vy0, vx1 && vy0, vx0 && vy1, vx1 && vy1};
    float wts[4] = {w00, w10, w01, w11};

    // fast path: corner RAW dots = normalized val / inv-norm at corner
    bool need = false;
    float dacc = 0.f;
#pragma unroll
    for (int c4 = 0; c4 < 4; c4++) {
        if (cvalid[c4]) {
            int du = cxs[c4] - u0m, dv = cys[c4] - v0m;
            if ((unsigned)du < (unsigned)nWm && (unsigned)dv < (unsigned)nHm) {
                float inv = invn[(size_t)b * HW + cys[c4] * WW + cxs[c4]];
                dacc = fmaf(wts[c4], vrow[dv * nWm + du] / inv, dacc);
            } else {
                need = true;  // uniform across block
            }
        }
    }

    float dms;
    if (need) {
        // rare fallback: per-channel descriptor gather
        const float* tgt = ddense + (size_t)(2 * b + 1) * CC * HW;
        int c = t;
        const float* ch = tgt + ((size_t)c << 16);
        float d00 = cvalid[0] ? ch[cys[0] * WW + cxs[0]] : 0.f;
        float d10 = cvalid[1] ? ch[cys[1] * WW + cxs[1]] : 0.f;
        float d01 = cvalid[2] ? ch[cys[2] * WW + cxs[2]] : 0.f;
        float d11 = cvalid[3] ? ch[cys[3] * WW + cxs[3]] : 0.f;
        float pd = d00 * wts[0] + d10 * wts[1] + d01 * wts[2] + d11 * wts[3];
        float dsum = blockSum(pd * s_src[c], s_red, t);
        dms = dsum / (float)CC;
    } else {
        dms = dacc / (float)CC;
    }

    if (t == 0) {
        const float* sch = sdense + (size_t)(2 * b + 1) * HW;
        float s00 = cvalid[0] ? sch[cys[0] * WW + cxs[0]] : 0.f;
        float s10 = cvalid[1] ? sch[cys[1] * WW + cxs[1]] : 0.f;
        float s01 = cvalid[2] ? sch[cys[2] * WW + cxs[2]] : 0.f;
        float s11 = cvalid[3] ? sch[cys[3] * WW + cxs[3]] : 0.f;
        float psc = s00 * wts[0] + s10 * wts[1] + s01 * wts[2] + s11 * wts[3];
        float sscore = kscores[(size_t)(2 * b) * NPTS + n];
        float wgt = 0.5f * (dms + 1.0f) * sscore * psc;
        out[2 * NPTS * BB + (size_t)b * NPTS + n] = wgt;
    }

    if (kpt == 0 && t < 2) out[3 * NPTS * BB + t] = 2.0f * (float)t;
}

// ================= fallback path (round-1, gather-based) ====================
__global__ __launch_bounds__(256) void prep_tgt(const float* __restrict__ dd,
                                                float* __restrict__ invn) {
    int idx = blockIdx.x * 256 + threadIdx.x;
    int b = idx >> 16, m = idx & 65535;
    const float* p = dd + (size_t)(2 * b + 1) * CC * HW + m;
    float ss = 0.f;
#pragma unroll 4
    for (int c = 0; c < CC; c++) {
        float x = p[(size_t)c << 16];
        ss += x * x;
    }
    invn[idx] = 1.0f / fmaxf(sqrtf(ss), EPSN);
}

__global__ __launch_bounds__(256) void matcher(const float* __restrict__ kscores,
                                               const float* __restrict__ sdense,
                                               const float* __restrict__ ddense,
                                               const float* __restrict__ kcoords,
                                               const float* __restrict__ srcn,
                                               const float* __restrict__ invn,
                                               float* __restrict__ out) {
    __shared__ float s_src[CC];
    __shared__ float s_red[4];
    int t = threadIdx.x;
    int kpt = blockIdx.x;
    int b = kpt >> 10, n = kpt & 1023;

    s_src[t] = srcn[(size_t)kpt * CC + t];

    float cu = kcoords[((size_t)(2 * b) * NPTS + n) * 2 + 0];
    float cv = kcoords[((size_t)(2 * b) * NPTS + n) * 2 + 1];
    int u = (int)truncf(cu), v = (int)truncf(cv);
    int u0 = max(0, u - KEEP), u1 = min(WW - 1, u + KEEP);
    int v0 = max(0, v - KEEP), v1 = min(HH - 1, v + KEEP);
    int nW = u1 - u0 + 1, nH = v1 - v0 + 1;
    int cnt = nW * nH;

    const float* tgt = ddense + (size_t)(2 * b + 1) * CC * HW;
    const float* inb = invn + (size_t)b * HW;
    __syncthreads();

    int p0 = t, p1 = t + 256, p2 = t + 512;
    bool g0 = p0 < cnt, g1 = p1 < cnt, g2 = p2 < cnt;
    int dv0 = p0 / nW, dv1 = p1 / nW, dv2 = p2 / nW;
    int uu0 = u0 + (p0 - dv0 * nW), uu1 = u0 + (p1 - dv1 * nW), uu2 = u0 + (p2 - dv2 * nW);
    int vv0 = v0 + dv0, vv1 = v0 + dv1, vv2 = v0 + dv2;
    int mi0 = g0 ? (vv0 * WW + uu0) : 0;
    int mi1 = g1 ? (vv1 * WW + uu1) : 0;
    int mi2 = g2 ? (vv2 * WW + uu2) : 0;

    const float* q0 = tgt + mi0;
    const float* q1 = tgt + mi1;
    const float* q2 = tgt + mi2;
    float a0 = 0.f, a1 = 0.f, a2 = 0.f;
#pragma unroll 4
    for (int c = 0; c < CC; c++) {
        float s = s_src[c];
        size_t off = (size_t)c << 16;
        a0 = fmaf(s, q0[off], a0);
        a1 = fmaf(s, q1[off], a1);
        a2 = fmaf(s, q2[off], a2);
    }
    float val0 = a0 * inb[mi0];
    float val1 = a1 * inb[mi1];
    float val2 = a2 * inb[mi2];

    float lm = fmaxf(fmaxf(g0 ? val0 : -INFINITY, g1 ? val1 : -INFINITY),
                     g2 ? val2 : -INFINITY);
    for (int o = 32; o > 0; o >>= 1) lm = fmaxf(lm, __shfl_down(lm, o, 64));
    if ((t & 63) == 0) s_red[t >> 6] = lm;
    __syncthreads();
    float m = fmaxf(fmaxf(s_red[0], s_red[1]), fmaxf(s_red[2], s_red[3]));
    m = fmaxf(m, 0.0f);

    float e0 = g0 ? expf(TINV * (val0 - m)) : 0.f;
    float e1 = g1 ? expf(TINV * (val1 - m)) : 0.f;
    float e2 = g2 ? expf(TINV * (val2 - m)) : 0.f;

    float se = blockSum(e0 + e1 + e2, s_red, t);
    float su = blockSum(e0 * uu0 + e1 * uu1 + e2 * uu2, s_red, t);
    float sv = blockSum(e0 * vv0 + e1 * vv1 + e2 * vv2, s_red, t);

    float em = expf(-TINV * m);
    float sumWinU = 0.5f * (float)(u0 + u1) * (float)nW * (float)nH;
    float sumWinV = 0.5f * (float)(v0 + v1) * (float)nH * (float)nW;
    float denom = se + (65536.0f - (float)cnt) * em;
    float pcu = (su + em * (S_ALL - sumWinU)) / denom;
    float pcv = (sv + em * (S_ALL - sumWinV)) / denom;

    if (t == 0) {
        out[((size_t)b * NPTS + n) * 2 + 0] = pcu;
        out[((size_t)b * NPTS + n) * 2 + 1] = pcv;
    }

    float x = pcu * (256.0f / 255.0f) - 0.5f;
    float y = pcv * (256.0f / 255.0f) - 0.5f;
    float x0f = floorf(x), y0f = floorf(y);
    float wx = x - x0f, wy = y - y0f;
    int xi0 = (int)x0f, yi0 = (int)y0f, xi1 = xi0 + 1, yi1 = yi0 + 1;
    float w00 = (1.f - wx) * (1.f - wy), w10 = wx * (1.f - wy);
    float w01 = (1.f - wx) * wy, w11 = wx * wy;
    bool vx0 = (xi0 >= 0) & (xi0 < WW), vx1 = (xi1 >= 0) & (xi1 < WW);
    bool vy0 = (yi0 >= 0) & (yi0 < HH), vy1 = (yi1 >= 0) & (yi1 < HH);
    int cx0 = min(max(xi0, 0), WW - 1), cx1 = min(max(xi1, 0), WW - 1);
    int cy0 = min(max(yi0, 0), HH - 1), cy1 = min(max(yi1, 0), HH - 1);

    {
        int c = t;
        const float* ch = tgt + ((size_t)c << 16);
        float d00 = (vx0 && vy0) ? ch[cy0 * WW + cx0] : 0.f;
        float d10 = (vx1 && vy0) ? ch[cy0 * WW + cx1] : 0.f;
        float d01 = (vx0 && vy1) ? ch[cy1 * WW + cx0] : 0.f;
        float d11 = (vx1 && vy1) ? ch[cy1 * WW + cx1] : 0.f;
        float pd = d00 * w00 + d10 * w10 + d01 * w01 + d11 * w11;
        float contrib = pd * s_src[c];
        float dsum = blockSum(contrib, s_red, t);
        if (t == 0) {
            float dms = dsum / (float)CC;
            const float* sch = sdense + (size_t)(2 * b + 1) * HW;
            float s00 = (vx0 && vy0) ? sch[cy0 * WW + cx0] : 0.f;
            float s10 = (vx1 && vy0) ? sch[cy0 * WW + cx1] : 0.f;
            float s01 = (vx0 && vy1) ? sch[cy1 * WW + cx0] : 0.f;
            float s11 = (vx1 && vy1) ? sch[cy1 * WW + cx1] : 0.f;
            float psc = s00 * w00 + s10 * w10 + s01 * w01 + s11 * w11;
            float sscore = kscores[(size_t)(2 * b) * NPTS + n];
            float wgt = 0.5f * (dms + 1.0f) * sscore * psc;
            out[2 * NPTS * BB + (size_t)b * NPTS + n] = wgt;
        }
    }

    if (kpt == 0 && t < 2) out[3 * NPTS * BB + t] = 2.0f * (float)t;
}

extern "C" void kernel_launch(void* const* d_in, const int* in_sizes, int n_in,
                              void* d_out, int out_size, void* d_ws, size_t ws_size,
                              hipStream_t stream) {
    const float* kscores = (const float*)d_in[0];  // [4,1,1024]
    const float* kdesc   = (const float*)d_in[1];  // [4,256,1024]
    const float* sdense  = (const float*)d_in[2];  // [4,1,256,256]
    const float* ddense  = (const float*)d_in[3];  // [4,256,256,256]
    const float* kcoords = (const float*)d_in[4];  // [4,1024,2]
    float* out = (float*)d_out;

    // workspace layout
    float* srcn = (float*)d_ws;                          // [2048][256]
    float* vals = srcn + (size_t)BB * NPTS * CC;         // [2048][864]
    float* invn = vals + (size_t)BB * NPTS * VSTRIDE;    // [2][65536]
    unsigned int* kparams = (unsigned int*)(invn + (size_t)BB * HW);  // [2048]
    size_t need = ((size_t)BB * NPTS * CC + (size_t)BB * NPTS * VSTRIDE +
                   (size_t)BB * HW + BB * NPTS) * 4;

    if (ws_size >= need) {
        hipLaunchKernelGGL(prep_src, dim3(BB * NPTS / KPB), dim3(256), 0, stream,
                           kdesc, kcoords, srcn, kparams);
        hipLaunchKernelGGL(corr_tiles, dim3(CNT), dim3(256), 0, stream,
                           ddense, srcn, kparams, vals, invn);
        hipLaunchKernelGGL(finish, dim3(BB * NPTS), dim3(256), 0, stream,
                           kscores, sdense, ddense, kcoords, srcn, vals, invn, out);
    } else {
        float* invn2 = srcn + (size_t)BB * NPTS * CC;  // [2][65536]
        hipLaunchKernelGGL(prep_src, dim3(BB * NPTS / KPB), dim3(256), 0, stream,
                           kdesc, kcoords, srcn, kparams);
        hipLaunchKernelGGL(prep_tgt, dim3(512), dim3(256), 0, stream, ddense, invn2);
        hipLaunchKernelGGL(matcher, dim3(BB * NPTS), dim3(256), 0, stream,
                           kscores, sdense, ddense, kcoords, srcn, invn2, out);
    }
}

// Round 14
// 79.446 us; speedup vs baseline: 1.0961x; 1.0961x over previous
//
#include <hip/hip_runtime.h>
#include <math.h>

// Problem constants (from reference)
#define HH 256
#define WW 256
#define CC 256
#define HW 65536
#define NPTS 1024
#define BB 2            // batch after indexing (BW=4, WINDOW_SIZE=2)
#define KEEP 13         // int(3.0 // 0.25 + 1)
#define KEEPM 14        // window + 1 margin for bilinear corners
#define TINV 100.0f     // 1 / SOFTMAX_TEMP
#define EPSN 1e-12f
#define S_ALL 8355840.0f  // sum over all HW positions of u (== of v)

// Tiling for the dense correlation pass: 16x4 px tiles, 256-thread blocks,
// 4-way channel-split lanes (quarter = lane>>4, pxg = lane&15).
#define CTW 16          // tile width (pixels, u)
#define CTH 4           // tile height (pixels, v)
#define CTUN 16         // tiles per row (256/16)
#define CTPB 1024       // tiles per batch (16 * 64)
#define CNT (BB * CTPB) // 2048 tiles total
#define CAPT 192        // max keypoints listed per tile (LDS list)
#define VSTRIDE 864     // padded per-keypoint margin capacity (>= 29*29=841)
#define BPAD 36         // B_lds row stride (floats): 16B-aligned k8 offsets
#define KPB 32          // keypoints per prep_src block (64 blocks)

// ---------------- prep: normalize src descriptors via LDS transpose ---------
// 64 blocks x 256 thr; block handles 32 keypoints (never straddles batches).
__global__ __launch_bounds__(256) void prep_src(const float* __restrict__ kdesc,
                                                const float* __restrict__ kcoords,
                                                float* __restrict__ srcn,
                                                unsigned int* __restrict__ kparams) {
    __shared__ float tr[KPB][CC + 1];   // [kpt][ch], pad -> conflict-free
    __shared__ float red[8][KPB];
    __shared__ float s_inv[KPB];
    int t = threadIdx.x;
    int kpt0 = blockIdx.x * KPB;
    int b = kpt0 >> 10;
    int n0 = kpt0 & 1023;
    const float* srcbase = kdesc + (size_t)(2 * b) * CC * NPTS;  // kp_inds = 2b

    int cj = t >> 5, nj = t & 31;
    for (int c0 = 0; c0 < CC; c0 += 8)   // coalesced 128B row reads
        tr[nj][c0 + cj] = srcbase[(size_t)(c0 + cj) * NPTS + n0 + nj];
    __syncthreads();

    {   // norms: kpt j = t&31, part p = t>>5 over 32 channels
        int j = t & 31, p = t >> 5;
        float ss = 0.f;
#pragma unroll 8
        for (int i = 0; i < 32; i++) {
            float x = tr[j][p * 32 + i];
            ss = fmaf(x, x, ss);
        }
        red[p][j] = ss;
    }
    __syncthreads();
    if (t < KPB) {
        float ss = 0.f;
#pragma unroll
        for (int p = 0; p < 8; p++) ss += red[p][t];
        s_inv[t] = 1.0f / fmaxf(sqrtf(ss), EPSN);
        int kpt = kpt0 + t;
        int n = kpt & 1023;
        float cu = kcoords[((size_t)(2 * b) * NPTS + n) * 2 + 0];
        float cv = kcoords[((size_t)(2 * b) * NPTS + n) * 2 + 1];
        int u = (int)truncf(cu), v = (int)truncf(cv);
        int u0m = max(0, u - KEEPM), u1m = min(WW - 1, u + KEEPM);
        int v0m = max(0, v - KEEPM), v1m = min(HH - 1, v + KEEPM);
        int nWm = u1m - u0m + 1, nHm = v1m - v0m + 1;
        kparams[kpt] = (unsigned)u0m | ((unsigned)v0m << 8) |
                       ((unsigned)nWm << 16) | ((unsigned)nHm << 24);
    }
    __syncthreads();
    for (int j = 0; j < KPB; j++)        // coalesced 1KB row writes
        srcn[(size_t)(kpt0 + j) * CC + t] = tr[j][t] * s_inv[j];
}

// ---------------- dense correlation per tile (with inline binning) ----------
// Block = 256 threads = one 16x4 pixel tile.
// lane = (quarter = lane>>4: channel mod 4, pxg = lane&15: pixel quad)
// kg = t>>6 (WAVE-UNIFORM 8-kpt group; 4 waves x 8 = 32 slots/chunk).
// Each load fetches 4 channels x 64 px of DISTINCT data; partial dots
// combined via 2-level shfl_xor(16,32) at chunk end.
__global__ __launch_bounds__(256) void corr_tiles(const float* __restrict__ ddense,
                                                  const float* __restrict__ srcn,
                                                  const unsigned int* __restrict__ kparams,
                                                  float* __restrict__ vals,
                                                  float* __restrict__ invn) {
    __shared__ __align__(16) float B_lds[CC][BPAD];
    __shared__ float s_inorm[CTW * CTH];   // 64 per-pixel inverse norms
    __shared__ int s_kid[CAPT];
    __shared__ unsigned int s_kp[CAPT];
    __shared__ int s_cnt;

    int tileg = blockIdx.x;
    int b = tileg >> 10, tl = tileg & 1023;
    int tv = tl >> 4, tu = tl & 15;
    int vb = tv * CTH, ub = tu * CTW;
    int t = threadIdx.x;
    if (t == 0) s_cnt = 0;
    __syncthreads();

    // inline binning: scan this batch's 1024 keypoints for margin-box overlap
    for (int i = t; i < NPTS; i += 256) {
        unsigned int kp = kparams[b * NPTS + i];
        int u0m = kp & 255, v0m = (kp >> 8) & 255;
        int nWm = (kp >> 16) & 255, nHm = (int)(kp >> 24);
        if (u0m <= ub + CTW - 1 && u0m + nWm - 1 >= ub &&
            v0m <= vb + CTH - 1 && v0m + nHm - 1 >= vb) {
            int slot = atomicAdd(&s_cnt, 1);
            if (slot < CAPT) {
                s_kid[slot] = b * NPTS + i;
                s_kp[slot] = kp;
            }
        }
    }
    __syncthreads();
    int nk = min(s_cnt, CAPT);
    if (nk == 0) return;

    int lane = t & 63;
    int quarter = lane >> 4;         // channel mod 4
    int pxg = lane & 15;             // pixel quad 0..15
    int kg = t >> 6;                 // wave id 0..3 -> 8-kpt group (uniform)
    int k8 = kg * 8;
    int px4 = pxg * 4;
    int wv = vb + (px4 >> 4), wu0 = ub + (px4 & 15);
    const float* abase = ddense + (size_t)(2 * b + 1) * CC * HW +
                         (size_t)quarter * HW + (size_t)wv * WW + wu0;

    for (int kc = 0; kc < nk; kc += 32) {
        int nkk = min(32, nk - kc);
#pragma unroll 4
        for (int i = 0; i < nkk; i++)
            B_lds[t][i] = srcn[(size_t)s_kid[kc + i] * CC + t];
        for (int i = nkk; i < 32; i++) B_lds[t][i] = 0.f;
        __syncthreads();

        float acc[4][8];
#pragma unroll
        for (int i = 0; i < 4; i++)
#pragma unroll
            for (int j = 0; j < 8; j++) acc[i][j] = 0.f;

        int kgn = (nkk + 7) >> 3;    // waves actually needed (uniform skip)
        if (kg < kgn) {
            float ss0 = 0.f, ss1 = 0.f, ss2 = 0.f, ss3 = 0.f;
            bool dos = (kg == 0) && (kc == 0);
#pragma unroll 4
            for (int cc = 0; cc < CC / 4; cc++) {   // 64 iters, 4-ch stride
                float4 av = *(const float4*)(abase + (size_t)cc * (4 * HW));
                const float* brow = &B_lds[4 * cc + quarter][k8];
                float b0 = brow[0], b1 = brow[1], b2 = brow[2], b3 = brow[3];
                float b4 = brow[4], b5 = brow[5], b6 = brow[6], b7 = brow[7];
                acc[0][0] = fmaf(av.x, b0, acc[0][0]);
                acc[0][1] = fmaf(av.x, b1, acc[0][1]);
                acc[0][2] = fmaf(av.x, b2, acc[0][2]);
                acc[0][3] = fmaf(av.x, b3, acc[0][3]);
                acc[0][4] = fmaf(av.x, b4, acc[0][4]);
                acc[0][5] = fmaf(av.x, b5, acc[0][5]);
                acc[0][6] = fmaf(av.x, b6, acc[0][6]);
                acc[0][7] = fmaf(av.x, b7, acc[0][7]);
                acc[1][0] = fmaf(av.y, b0, acc[1][0]);
                acc[1][1] = fmaf(av.y, b1, acc[1][1]);
                acc[1][2] = fmaf(av.y, b2, acc[1][2]);
                acc[1][3] = fmaf(av.y, b3, acc[1][3]);
                acc[1][4] = fmaf(av.y, b4, acc[1][4]);
                acc[1][5] = fmaf(av.y, b5, acc[1][5]);
                acc[1][6] = fmaf(av.y, b6, acc[1][6]);
                acc[1][7] = fmaf(av.y, b7, acc[1][7]);
                acc[2][0] = fmaf(av.z, b0, acc[2][0]);
                acc[2][1] = fmaf(av.z, b1, acc[2][1]);
                acc[2][2] = fmaf(av.z, b2, acc[2][2]);
                acc[2][3] = fmaf(av.z, b3, acc[2][3]);
                acc[2][4] = fmaf(av.z, b4, acc[2][4]);
                acc[2][5] = fmaf(av.z, b5, acc[2][5]);
                acc[2][6] = fmaf(av.z, b6, acc[2][6]);
                acc[2][7] = fmaf(av.z, b7, acc[2][7]);
                acc[3][0] = fmaf(av.w, b0, acc[3][0]);
                acc[3][1] = fmaf(av.w, b1, acc[3][1]);
                acc[3][2] = fmaf(av.w, b2, acc[3][2]);
                acc[3][3] = fmaf(av.w, b3, acc[3][3]);
                acc[3][4] = fmaf(av.w, b4, acc[3][4]);
                acc[3][5] = fmaf(av.w, b5, acc[3][5]);
                acc[3][6] = fmaf(av.w, b6, acc[3][6]);
                acc[3][7] = fmaf(av.w, b7, acc[3][7]);
                if (dos) {          // wave-0-only pixel-norm accumulation
                    ss0 = fmaf(av.x, av.x, ss0);
                    ss1 = fmaf(av.y, av.y, ss1);
                    ss2 = fmaf(av.z, av.z, ss2);
                    ss3 = fmaf(av.w, av.w, ss3);
                }
            }
            // combine the 4 channel-quarters: butterfly over lane bits 4,5
#pragma unroll
            for (int i = 0; i < 4; i++)
#pragma unroll
                for (int j = 0; j < 8; j++) {
                    acc[i][j] += __shfl_xor(acc[i][j], 16, 64);
                    acc[i][j] += __shfl_xor(acc[i][j], 32, 64);
                }
            if (dos) {
                ss0 += __shfl_xor(ss0, 16, 64);
                ss0 += __shfl_xor(ss0, 32, 64);
                ss1 += __shfl_xor(ss1, 16, 64);
                ss1 += __shfl_xor(ss1, 32, 64);
                ss2 += __shfl_xor(ss2, 16, 64);
                ss2 += __shfl_xor(ss2, 32, 64);
                ss3 += __shfl_xor(ss3, 16, 64);
                ss3 += __shfl_xor(ss3, 32, 64);
                if (quarter == 0) {
                    float i0 = 1.0f / fmaxf(sqrtf(ss0), EPSN);
                    float i1 = 1.0f / fmaxf(sqrtf(ss1), EPSN);
                    float i2 = 1.0f / fmaxf(sqrtf(ss2), EPSN);
                    float i3 = 1.0f / fmaxf(sqrtf(ss3), EPSN);
                    s_inorm[px4 + 0] = i0;
                    s_inorm[px4 + 1] = i1;
                    s_inorm[px4 + 2] = i2;
                    s_inorm[px4 + 3] = i3;
                    float* ip = invn + (size_t)b * HW + wv * WW + wu0;
                    ip[0] = i0; ip[1] = i1; ip[2] = i2; ip[3] = i3;
                }
            }
        }
        if (kc == 0) __syncthreads();   // publish s_inorm before first scatter

        // scatter NORMALIZED window values from quarter-0 lanes
        // j-outer: decode each keypoint ONCE, hoist the row (dv) check.
        if (quarter == 0) {
            float iv0 = s_inorm[px4 + 0], iv1 = s_inorm[px4 + 1];
            float iv2 = s_inorm[px4 + 2], iv3 = s_inorm[px4 + 3];
#pragma unroll
            for (int j = 0; j < 8; j++) {
                int s = k8 + j;
                if (s < nkk) {
                    unsigned int kp = s_kp[kc + s];
                    int u0m = kp & 255, v0m = (kp >> 8) & 255;
                    int nWm = (kp >> 16) & 255, nHm = (int)(kp >> 24);
                    int dv = wv - v0m;
                    if ((unsigned)dv < (unsigned)nHm) {
                        int du0 = wu0 - u0m;
                        float* vp = vals + (size_t)s_kid[kc + s] * VSTRIDE +
                                    dv * nWm;
                        if ((unsigned)(du0 + 0) < (unsigned)nWm)
                            vp[du0 + 0] = acc[0][j] * iv0;
                        if ((unsigned)(du0 + 1) < (unsigned)nWm)
                            vp[du0 + 1] = acc[1][j] * iv1;
                        if ((unsigned)(du0 + 2) < (unsigned)nWm)
                            vp[du0 + 2] = acc[2][j] * iv2;
                        if ((unsigned)(du0 + 3) < (unsigned)nWm)
                            vp[du0 + 3] = acc[3][j] * iv3;
                    }
                }
            }
        }
        __syncthreads();   // protect B_lds before next chunk's staging
    }
}

// ---------------- reductions helper -----------------------------------------
__device__ inline float blockSum(float v, float* sred, int t) {
    for (int o = 32; o > 0; o >>= 1) v += __shfl_down(v, o, 64);
    __syncthreads();
    if ((t & 63) == 0) sred[t >> 6] = v;
    __syncthreads();
    return sred[0] + sred[1] + sred[2] + sred[3];
}

// ---------------- finish: softmax-argmax + resample from normalized vals ----
__global__ __launch_bounds__(256) void finish(const float* __restrict__ kscores,
                                              const float* __restrict__ sdense,
                                              const float* __restrict__ ddense,
                                              const float* __restrict__ kcoords,
                                              const float* __restrict__ srcn,
                                              const float* __restrict__ vals,
                                              const float* __restrict__ invn,
                                              float* __restrict__ out) {
    __shared__ float s_src[CC];
    __shared__ float s_red[4];
    int t = threadIdx.x;
    int kpt = blockIdx.x;
    int b = kpt >> 10, n = kpt & 1023;

    s_src[t] = srcn[(size_t)kpt * CC + t];

    float cu = kcoords[((size_t)(2 * b) * NPTS + n) * 2 + 0];
    float cv = kcoords[((size_t)(2 * b) * NPTS + n) * 2 + 1];
    int u = (int)truncf(cu), v = (int)truncf(cv);
    int u0 = max(0, u - KEEP), u1 = min(WW - 1, u + KEEP);
    int v0 = max(0, v - KEEP), v1 = min(HH - 1, v + KEEP);
    int nW = u1 - u0 + 1, nH = v1 - v0 + 1;
    int cnt = nW * nH;
    int u0m = max(0, u - KEEPM), u1m = min(WW - 1, u + KEEPM);
    int v0m = max(0, v - KEEPM), v1m = min(HH - 1, v + KEEPM);
    int nWm = u1m - u0m + 1, nHm = v1m - v0m + 1;
    int cntm = nWm * nHm;

    const float* vrow = vals + (size_t)kpt * VSTRIDE;
    __syncthreads();

    float valk[4];
    int puk[4], pvk[4];
    bool gk[4];
    float lm = -INFINITY;
#pragma unroll
    for (int k = 0; k < 4; k++) {
        int p = t + k * 256;
        bool gm = p < cntm;
        int pp = gm ? p : 0;
        int dvm = pp / nWm, dum = pp - dvm * nWm;
        int pu = u0m + dum, pv = v0m + dvm;
        bool inw = gm && pu >= u0 && pu <= u1 && pv >= v0 && pv <= v1;
        float val = inw ? vrow[pp] : 0.f;   // already normalized
        valk[k] = val;
        puk[k] = pu;
        pvk[k] = pv;
        gk[k] = inw;
        if (inw) lm = fmaxf(lm, val);
    }

    for (int o = 32; o > 0; o >>= 1) lm = fmaxf(lm, __shfl_down(lm, o, 64));
    if ((t & 63) == 0) s_red[t >> 6] = lm;
    __syncthreads();
    float m = fmaxf(fmaxf(s_red[0], s_red[1]), fmaxf(s_red[2], s_red[3]));
    m = fmaxf(m, 0.0f);

    float pse = 0.f, psu = 0.f, psv = 0.f;
#pragma unroll
    for (int k = 0; k < 4; k++) {
        float e = gk[k] ? expf(TINV * (valk[k] - m)) : 0.f;
        pse += e;
        psu = fmaf(e, (float)puk[k], psu);
        psv = fmaf(e, (float)pvk[k], psv);
    }
    float se = blockSum(pse, s_red, t);
    float su = blockSum(psu, s_red, t);
    float sv = blockSum(psv, s_red, t);

    float em = expf(-TINV * m);
    float sumWinU = 0.5f * (float)(u0 + u1) * (float)nW * (float)nH;
    float sumWinV = 0.5f * (float)(v0 + v1) * (float)nH * (float)nW;
    float denom = se + (65536.0f - (float)cnt) * em;
    float pcu = (su + em * (S_ALL - sumWinU)) / denom;
    float pcv = (sv + em * (S_ALL - sumWinV)) / denom;

    if (t == 0) {
        out[((size_t)b * NPTS + n) * 2 + 0] = pcu;
        out[((size_t)b * NPTS + n) * 2 + 1] = pcv;
    }

    // bilinear resample (align_corners=False, zero padding)
    float x = pcu * (256.0f / 255.0f) - 0.5f;
    float y = pcv * (256.0f / 255.0f) - 0.5f;
    float x0f = floorf(x), y0f = floorf(y);
    float wx = x - x0f, wy = y - y0f;
    int xi0 = (int)x0f, yi0 = (int)y0f, xi1 = xi0 + 1, yi1 = yi0 + 1;
    float w00 = (1.f - wx) * (1.f - wy), w10 = wx * (1.f - wy);
    float w01 = (1.f - wx) * wy, w11 = wx * wy;
    bool vx0 = (xi0 >= 0) & (xi0 < WW), vx1 = (xi1 >= 0) & (xi1 < WW);
    bool vy0 = (yi0 >= 0) & (yi0 < HH), vy1 = (yi1 >= 0) & (yi1 < HH);
    int cx0 = min(max(xi0, 0), WW - 1), cx1 = min(max(xi1, 0), WW - 1);
    int cy0 = min(max(yi0, 0), HH - 1), cy1 = min(max(yi1, 0), HH - 1);

    int cxs[4] = {cx0, cx1, cx0, cx1};
    int cys[4] = {cy0, cy0, cy1, cy1};
    bool cvalid[4] = {vx0 && vy0, vx1 && vy0, vx0 && vy1, vx1 && vy1};
    float wts[4] = {w00, w10, w01, w11};

    // fast path: corner RAW dots = normalized val / inv-norm at corner
    bool need = false;
    float dacc = 0.f;
#pragma unroll
    for (int c4 = 0; c4 < 4; c4++) {
        if (cvalid[c4]) {
            int du = cxs[c4] - u0m, dv = cys[c4] - v0m;
            if ((unsigned)du < (unsigned)nWm && (unsigned)dv < (unsigned)nHm) {
                float inv = invn[(size_t)b * HW + cys[c4] * WW + cxs[c4]];
                dacc = fmaf(wts[c4], vrow[dv * nWm + du] / inv, dacc);
            } else {
                need = true;  // uniform across block
            }
        }
    }

    float dms;
    if (need) {
        // rare fallback: per-channel descriptor gather
        const float* tgt = ddense + (size_t)(2 * b + 1) * CC * HW;
        int c = t;
        const float* ch = tgt + ((size_t)c << 16);
        float d00 = cvalid[0] ? ch[cys[0] * WW + cxs[0]] : 0.f;
        float d10 = cvalid[1] ? ch[cys[1] * WW + cxs[1]] : 0.f;
        float d01 = cvalid[2] ? ch[cys[2] * WW + cxs[2]] : 0.f;
        float d11 = cvalid[3] ? ch[cys[3] * WW + cxs[3]] : 0.f;
        float pd = d00 * wts[0] + d10 * wts[1] + d01 * wts[2] + d11 * wts[3];
        float dsum = blockSum(pd * s_src[c], s_red, t);
        dms = dsum / (float)CC;
    } else {
        dms = dacc / (float)CC;
    }

    if (t == 0) {
        const float* sch = sdense + (size_t)(2 * b + 1) * HW;
        float s00 = cvalid[0] ? sch[cys[0] * WW + cxs[0]] : 0.f;
        float s10 = cvalid[1] ? sch[cys[1] * WW + cxs[1]] : 0.f;
        float s01 = cvalid[2] ? sch[cys[2] * WW + cxs[2]] : 0.f;
        float s11 = cvalid[3] ? sch[cys[3] * WW + cxs[3]] : 0.f;
        float psc = s00 * wts[0] + s10 * wts[1] + s01 * wts[2] + s11 * wts[3];
        float sscore = kscores[(size_t)(2 * b) * NPTS + n];
        float wgt = 0.5f * (dms + 1.0f) * sscore * psc;
        out[2 * NPTS * BB + (size_t)b * NPTS + n] = wgt;
    }

    if (kpt == 0 && t < 2) out[3 * NPTS * BB + t] = 2.0f * (float)t;
}

// ================= fallback path (round-1, gather-based) ====================
__global__ __launch_bounds__(256) void prep_tgt(const float* __restrict__ dd,
                                                float* __restrict__ invn) {
    int idx = blockIdx.x * 256 + threadIdx.x;
    int b = idx >> 16, m = idx & 65535;
    const float* p = dd + (size_t)(2 * b + 1) * CC * HW + m;
    float ss = 0.f;
#pragma unroll 4
    for (int c = 0; c < CC; c++) {
        float x = p[(size_t)c << 16];
        ss += x * x;
    }
    invn[idx] = 1.0f / fmaxf(sqrtf(ss), EPSN);
}

__global__ __launch_bounds__(256) void matcher(const float* __restrict__ kscores,
                                               const float* __restrict__ sdense,
                                               const float* __restrict__ ddense,
                                               const float* __restrict__ kcoords,
                                               const float* __restrict__ srcn,
                                               const float* __restrict__ invn,
                                               float* __restrict__ out) {
    __shared__ float s_src[CC];
    __shared__ float s_red[4];
    int t = threadIdx.x;
    int kpt = blockIdx.x;
    int b = kpt >> 10, n = kpt & 1023;

    s_src[t] = srcn[(size_t)kpt * CC + t];

    float cu = kcoords[((size_t)(2 * b) * NPTS + n) * 2 + 0];
    float cv = kcoords[((size_t)(2 * b) * NPTS + n) * 2 + 1];
    int u = (int)truncf(cu), v = (int)truncf(cv);
    int u0 = max(0, u - KEEP), u1 = min(WW - 1, u + KEEP);
    int v0 = max(0, v - KEEP), v1 = min(HH - 1, v + KEEP);
    int nW = u1 - u0 + 1, nH = v1 - v0 + 1;
    int cnt = nW * nH;

    const float* tgt = ddense + (size_t)(2 * b + 1) * CC * HW;
    const float* inb = invn + (size_t)b * HW;
    __syncthreads();

    int p0 = t, p1 = t + 256, p2 = t + 512;
    bool g0 = p0 < cnt, g1 = p1 < cnt, g2 = p2 < cnt;
    int dv0 = p0 / nW, dv1 = p1 / nW, dv2 = p2 / nW;
    int uu0 = u0 + (p0 - dv0 * nW), uu1 = u0 + (p1 - dv1 * nW), uu2 = u0 + (p2 - dv2 * nW);
    int vv0 = v0 + dv0, vv1 = v0 + dv1, vv2 = v0 + dv2;
    int mi0 = g0 ? (vv0 * WW + uu0) : 0;
    int mi1 = g1 ? (vv1 * WW + uu1) : 0;
    int mi2 = g2 ? (vv2 * WW + uu2) : 0;

    const float* q0 = tgt + mi0;
    const float* q1 = tgt + mi1;
    const float* q2 = tgt + mi2;
    float a0 = 0.f, a1 = 0.f, a2 = 0.f;
#pragma unroll 4
    for (int c = 0; c < CC; c++) {
        float s = s_src[c];
        size_t off = (size_t)c << 16;
        a0 = fmaf(s, q0[off], a0);
        a1 = fmaf(s, q1[off], a1);
        a2 = fmaf(s, q2[off], a2);
    }
    float val0 = a0 * inb[mi0];
    float val1 = a1 * inb[mi1];
    float val2 = a2 * inb[mi2];

    float lm = fmaxf(fmaxf(g0 ? val0 : -INFINITY, g1 ? val1 : -INFINITY),
                     g2 ? val2 : -INFINITY);
    for (int o = 32; o > 0; o >>= 1) lm = fmaxf(lm, __shfl_down(lm, o, 64));
    if ((t & 63) == 0) s_red[t >> 6] = lm;
    __syncthreads();
    float m = fmaxf(fmaxf(s_red[0], s_red[1]), fmaxf(s_red[2], s_red[3]));
    m = fmaxf(m, 0.0f);

    float e0 = g0 ? expf(TINV * (val0 - m)) : 0.f;
    float e1 = g1 ? expf(TINV * (val1 - m)) : 0.f;
    float e2 = g2 ? expf(TINV * (val2 - m)) : 0.f;

    float se = blockSum(e0 + e1 + e2, s_red, t);
    float su = blockSum(e0 * uu0 + e1 * uu1 + e2 * uu2, s_red, t);
    float sv = blockSum(e0 * vv0 + e1 * vv1 + e2 * vv2, s_red, t);

    float em = expf(-TINV * m);
    float sumWinU = 0.5f * (float)(u0 + u1) * (float)nW * (float)nH;
    float sumWinV = 0.5f * (float)(v0 + v1) * (float)nH * (float)nW;
    float denom = se + (65536.0f - (float)cnt) * em;
    float pcu = (su + em * (S_ALL - sumWinU)) / denom;
    float pcv = (sv + em * (S_ALL - sumWinV)) / denom;

    if (t == 0) {
        out[((size_t)b * NPTS + n) * 2 + 0] = pcu;
        out[((size_t)b * NPTS + n) * 2 + 1] = pcv;
    }

    float x = pcu * (256.0f / 255.0f) - 0.5f;
    float y = pcv * (256.0f / 255.0f) - 0.5f;
    float x0f = floorf(x), y0f = floorf(y);
    float wx = x - x0f, wy = y - y0f;
    int xi0 = (int)x0f, yi0 = (int)y0f, xi1 = xi0 + 1, yi1 = yi0 + 1;
    float w00 = (1.f - wx) * (1.f - wy), w10 = wx * (1.f - wy);
    float w01 = (1.f - wx) * wy, w11 = wx * wy;
    bool vx0 = (xi0 >= 0) & (xi0 < WW), vx1 = (xi1 >= 0) & (xi1 < WW);
    bool vy0 = (yi0 >= 0) & (yi0 < HH), vy1 = (yi1 >= 0) & (yi1 < HH);
    int cx0 = min(max(xi0, 0), WW - 1), cx1 = min(max(xi1, 0), WW - 1);
    int cy0 = min(max(yi0, 0), HH - 1), cy1 = min(max(yi1, 0), HH - 1);

    {
        int c = t;
        const float* ch = tgt + ((size_t)c << 16);
        float d00 = (vx0 && vy0) ? ch[cy0 * WW + cx0] : 0.f;
        float d10 = (vx1 && vy0) ? ch[cy0 * WW + cx1] : 0.f;
        float d01 = (vx0 && vy1) ? ch[cy1 * WW + cx0] : 0.f;
        float d11 = (vx1 && vy1) ? ch[cy1 * WW + cx1] : 0.f;
        float pd = d00 * w00 + d10 * w10 + d01 * w01 + d11 * w11;
        float contrib = pd * s_src[c];
        float dsum = blockSum(contrib, s_red, t);
        if (t == 0) {
            float dms = dsum / (float)CC;
            const float* sch = sdense + (size_t)(2 * b + 1) * HW;
            float s00 = (vx0 && vy0) ? sch[cy0 * WW + cx0] : 0.f;
            float s10 = (vx1 && vy0) ? sch[cy0 * WW + cx1] : 0.f;
            float s01 = (vx0 && vy1) ? sch[cy1 * WW + cx0] : 0.f;
            float s11 = (vx1 && vy1) ? sch[cy1 * WW + cx1] : 0.f;
            float psc = s00 * w00 + s10 * w10 + s01 * w01 + s11 * w11;
            float sscore = kscores[(size_t)(2 * b) * NPTS + n];
            float wgt = 0.5f * (dms + 1.0f) * sscore * psc;
            out[2 * NPTS * BB + (size_t)b * NPTS + n] = wgt;
        }
    }

    if (kpt == 0 && t < 2) out[3 * NPTS * BB + t] = 2.0f * (float)t;
}

extern "C" void kernel_launch(void* const* d_in, const int* in_sizes, int n_in,
                              void* d_out, int out_size, void* d_ws, size_t ws_size,
                              hipStream_t stream) {
    const float* kscores = (const float*)d_in[0];  // [4,1,1024]
    const float* kdesc   = (const float*)d_in[1];  // [4,256,1024]
    const float* sdense  = (const float*)d_in[2];  // [4,1,256,256]
    const float* ddense  = (const float*)d_in[3];  // [4,256,256,256]
    const float* kcoords = (const float*)d_in[4];  // [4,1024,2]
    float* out = (float*)d_out;

    // workspace layout
    float* srcn = (float*)d_ws;                          // [2048][256]
    float* vals = srcn + (size_t)BB * NPTS * CC;         // [2048][864]
    float* invn = vals + (size_t)BB * NPTS * VSTRIDE;    // [2][65536]
    unsigned int* kparams = (unsigned int*)(invn + (size_t)BB * HW);  // [2048]
    size_t need = ((size_t)BB * NPTS * CC + (size_t)BB * NPTS * VSTRIDE +
                   (size_t)BB * HW + BB * NPTS) * 4;

    if (ws_size >= need) {
        hipLaunchKernelGGL(prep_src, dim3(BB * NPTS / KPB), dim3(256), 0, stream,
                           kdesc, kcoords, srcn, kparams);
        hipLaunchKernelGGL(corr_tiles, dim3(CNT), dim3(256), 0, stream,
                           ddense, srcn, kparams, vals, invn);
        hipLaunchKernelGGL(finish, dim3(BB * NPTS), dim3(256), 0, stream,
                           kscores, sdense, ddense, kcoords, srcn, vals, invn, out);
    } else {
        float* invn2 = srcn + (size_t)BB * NPTS * CC;  // [2][65536]
        hipLaunchKernelGGL(prep_src, dim3(BB * NPTS / KPB), dim3(256), 0, stream,
                           kdesc, kcoords, srcn, kparams);
        hipLaunchKernelGGL(prep_tgt, dim3(512), dim3(256), 0, stream, ddense, invn2);
        hipLaunchKernelGGL(matcher, dim3(BB * NPTS), dim3(256), 0, stream,
                           kscores, sdense, ddense, kcoords, srcn, invn2, out);
    }
}